// Round 1
// baseline (8158.550 us; speedup 1.0000x reference)
//
#include <hip/hip_runtime.h>
#include <stdint.h>

// PolicyNetRSNNPB: 2-layer LIF RSNN + leaky readout, T=64 x REPEAT=2 = 128 steps.
// Key structure: batch samples are fully independent -> 1 workgroup per sample,
// whole 128-step scan inside one kernel, state in LDS, no grid sync.
// Spikes are binary -> s@W done as sparse gather-sum of W rows via 64-bit
// ballot masks (exact fp32 adds, no multiplies).
// xt@Wi + bi precomputed for all 64 unique t into d_ws (256 MB) when it fits.

#define NSTEPS 128
#define NB 512
#define HDIM 2048
#define INDIM 128
#define AOUT 64           // 2*A
#define THREADS 512
#define CPT (HDIM / THREADS)   // 4 columns per thread
#define NWORDS (HDIM / 64)     // 32 mask words

__device__ __forceinline__ float dcy_m() { return 0.8187307530779818f; }
__device__ __forceinline__ float dcy_s() { return 0.6065306597126334f; }
__device__ __forceinline__ float scl_m() { return 0.18126924692201818f; }

// ---------------- XW precompute: XW[t*NB+n][h] = bi[h] + x(t,n,:) @ Wi ----------------
// grid: (8 col-slices of 256, 2048 row-groups of 16), block 256
__global__ __launch_bounds__(256) void xw_kernel(
    const float* __restrict__ state, const float* __restrict__ target,
    const float* __restrict__ Wi, const float* __restrict__ bi,
    float* __restrict__ XW) {
  __shared__ float xl[16][INDIM];
  const int tid = threadIdx.x;
  const int col = blockIdx.x * 256 + tid;
  const int r0 = blockIdx.y * 16;

  for (int idx = tid; idx < 16 * INDIM; idx += 256) {
    int r = idx >> 7, k = idx & 127;
    int g = r0 + r;              // g = t*NB + n
    int t = g >> 9, n = g & 511;
    float v = (k < 64) ? state[((size_t)(t * NB + n)) * 64 + k]
                       : target[((size_t)(t * NB + n)) * 64 + (k - 64)];
    xl[r][k] = v;
  }
  __syncthreads();

  float acc[16];
  float b = bi[col];
#pragma unroll
  for (int r = 0; r < 16; ++r) acc[r] = b;
  for (int k = 0; k < INDIM; ++k) {
    float w = Wi[(size_t)k * HDIM + col];
#pragma unroll
    for (int r = 0; r < 16; ++r) acc[r] = fmaf(xl[r][k], w, acc[r]);
  }
#pragma unroll
  for (int r = 0; r < 16; ++r) XW[(size_t)(r0 + r) * HDIM + col] = acc[r];
}

// ---------------- main persistent per-sample kernel ----------------
__global__ __launch_bounds__(THREADS) void rsnn_kernel(
    const float* __restrict__ state, const float* __restrict__ target,
    const float* __restrict__ Wi, const float* __restrict__ bi,
    const float* __restrict__ Vr, const float* __restrict__ Wf,
    const float* __restrict__ bf, const float* __restrict__ Wo,
    const float* __restrict__ bo, const float* __restrict__ XW,
    float* __restrict__ out, int use_xw) {
  __shared__ float syn1[HDIM], mem1[HDIM], syn2[HDIM], mem2[HDIM];
  __shared__ unsigned long long m1[NWORDS], m2[NWORDS];
  __shared__ float synr[AOUT], memr[AOUT], roprev[AOUT];
  __shared__ float xbuf[INDIM];
  __shared__ float xw_lds[HDIM];   // fallback path only

  const int n = blockIdx.x;
  const int tid = threadIdx.x;
  const int wv = tid >> 6;
  const int lane = tid & 63;

  // zero-init state
  for (int h = tid; h < HDIM; h += THREADS) {
    syn1[h] = 0.0f; mem1[h] = 0.0f; syn2[h] = 0.0f; mem2[h] = 0.0f;
  }
  if (tid < NWORDS) { m1[tid] = 0ULL; m2[tid] = 0ULL; }
  if (tid < AOUT) { synr[tid] = 0.0f; memr[tid] = 0.0f; roprev[tid] = 0.0f; }
  __syncthreads();

  // hoist biases (bf for layer2; bo for readout)
  float bfr[CPT];
#pragma unroll
  for (int i = 0; i < CPT; ++i) bfr[i] = bf[i * THREADS + tid];
  float bor = (tid < AOUT) ? bo[tid] : 0.0f;

  const float dm = dcy_m(), ds = dcy_s(), sm = scl_m();

  for (int step = 0; step < NSTEPS; ++step) {
    const int t = step >> 1;

    // ---- fallback: compute xw into LDS once per unique t ----
    if (!use_xw) {
      if ((step & 1) == 0) {
        if (tid < INDIM) {
          xbuf[tid] = (tid < 64) ? state[((size_t)(t * NB + n)) * 64 + tid]
                                 : target[((size_t)(t * NB + n)) * 64 + (tid - 64)];
        }
        __syncthreads();
#pragma unroll
        for (int i = 0; i < CPT; ++i) {
          int h = i * THREADS + tid;
          float a = bi[h];
          for (int k = 0; k < INDIM; ++k) a = fmaf(xbuf[k], Wi[(size_t)k * HDIM + h], a);
          xw_lds[h] = a;
        }
        __syncthreads();
      }
    }

    // ================= layer 1: I1 = xw + s1_old @ Vr =================
    float acc[CPT];
    if (use_xw) {
      const float* xwrow = XW + ((size_t)(t * NB + n)) * HDIM;
#pragma unroll
      for (int i = 0; i < CPT; ++i) acc[i] = xwrow[i * THREADS + tid];
    } else {
#pragma unroll
      for (int i = 0; i < CPT; ++i) acc[i] = xw_lds[i * THREADS + tid];
    }
    for (int w = 0; w < NWORDS; ++w) {
      unsigned long long mw = m1[w];     // block-uniform broadcast
      const int kbase = w << 6;
      while (mw) {
        int k = kbase + __builtin_ctzll(mw);
        mw &= (mw - 1);
        const float* row = Vr + (size_t)k * HDIM;
#pragma unroll
        for (int i = 0; i < CPT; ++i) acc[i] += row[i * THREADS + tid];
      }
    }
    // LIF update (uses OLD s1 bit for reset, OLD syn1/mem1)
    float nm1[CPT];
#pragma unroll
    for (int i = 0; i < CPT; ++i) {
      int h = i * THREADS + tid;
      float so = (float)((m1[i * (THREADS / 64) + wv] >> lane) & 1ULL);
      float nmem = (dm * mem1[h] + sm * syn1[h]) * (1.0f - so);
      float nsyn = ds * syn1[h] + acc[i];
      mem1[h] = nmem; syn1[h] = nsyn;
      nm1[i] = nmem;
    }
    __syncthreads();                     // all reads of old m1 complete
#pragma unroll
    for (int i = 0; i < CPT; ++i) {
      unsigned long long bm = __ballot((nm1[i] - 1.0f) > 0.0f);
      if (lane == 0) m1[i * (THREADS / 64) + wv] = bm;
    }
    __syncthreads();                     // new m1 (= ns1) visible

    // ================= layer 2: I2 = bf + ns1 @ Wf =================
    float acc2[CPT];
#pragma unroll
    for (int i = 0; i < CPT; ++i) acc2[i] = bfr[i];
    for (int w = 0; w < NWORDS; ++w) {
      unsigned long long mw = m1[w];
      const int kbase = w << 6;
      while (mw) {
        int k = kbase + __builtin_ctzll(mw);
        mw &= (mw - 1);
        const float* row = Wf + (size_t)k * HDIM;
#pragma unroll
        for (int i = 0; i < CPT; ++i) acc2[i] += row[i * THREADS + tid];
      }
    }
    float nm2[CPT];
#pragma unroll
    for (int i = 0; i < CPT; ++i) {
      int h = i * THREADS + tid;
      float so = (float)((m2[i * (THREADS / 64) + wv] >> lane) & 1ULL);
      float nmem = (dm * mem2[h] + sm * syn2[h]) * (1.0f - so);
      float nsyn = ds * syn2[h] + acc2[i];
      mem2[h] = nmem; syn2[h] = nsyn;
      nm2[i] = nmem;
    }
    __syncthreads();                     // all reads of old m2 + m1 complete
#pragma unroll
    for (int i = 0; i < CPT; ++i) {
      unsigned long long bm = __ballot((nm2[i] - 1.0f) > 0.0f);
      if (lane == 0) m2[i * (THREADS / 64) + wv] = bm;
    }
    __syncthreads();                     // new m2 (= ns2) visible

    // ================= readout: Ir = bo + ns2 @ Wo =================
    if (tid < AOUT) {
      float a = bor;
      for (int w = 0; w < NWORDS; ++w) {
        unsigned long long mw = m2[w];
        const int kbase = w << 6;
        while (mw) {
          int k = kbase + __builtin_ctzll(mw);
          mw &= (mw - 1);
          a += Wo[(size_t)k * AOUT + tid];
        }
      }
      float nmemr = dm * memr[tid] + sm * synr[tid];   // old synr!
      float nsynr = ds * synr[tid] + a;
      memr[tid] = nmemr; synr[tid] = nsynr;
      if (step & 1) {
        float v = 0.5f * (roprev[tid] + nmemr);
        size_t base = ((size_t)t * NB + n) * 32;
        if (tid < 32) out[base + tid] = v;
        else          out[(size_t)(64 * NB * 32) + base + (tid - 32)] = v;
      } else {
        roprev[tid] = nmemr;
      }
    }
    // no sync needed here: m2 next written only after a sync all threads reach
  }
}

extern "C" void kernel_launch(void* const* d_in, const int* in_sizes, int n_in,
                              void* d_out, int out_size, void* d_ws, size_t ws_size,
                              hipStream_t stream) {
  const float* state  = (const float*)d_in[0];
  const float* target = (const float*)d_in[1];
  const float* Wi     = (const float*)d_in[2];
  const float* bi     = (const float*)d_in[3];
  const float* Vr     = (const float*)d_in[4];
  const float* Wf     = (const float*)d_in[5];
  const float* bf     = (const float*)d_in[6];
  const float* Wo     = (const float*)d_in[7];
  const float* bo     = (const float*)d_in[8];
  float* out = (float*)d_out;

  const size_t xw_bytes = (size_t)64 * NB * HDIM * sizeof(float);  // 256 MB
  int use_xw = (ws_size >= xw_bytes) ? 1 : 0;
  float* XW = (float*)d_ws;

  if (use_xw) {
    xw_kernel<<<dim3(8, 2048), 256, 0, stream>>>(state, target, Wi, bi, XW);
  }
  rsnn_kernel<<<NB, THREADS, 0, stream>>>(state, target, Wi, bi, Vr, Wf, bf,
                                          Wo, bo, XW, out, use_xw);
}